// Round 1
// baseline (238.536 us; speedup 1.0000x reference)
//
#include <hip/hip_runtime.h>
#include <hip/hip_bf16.h>
#include <stdint.h>

typedef unsigned short u16;
typedef unsigned int   u32;

#define N_DIM  1024
#define IN_DIM 1024
#define H_DIM  64
#define BATCH  16

typedef __bf16 bf16x8 __attribute__((ext_vector_type(8)));
typedef float  f32x4  __attribute__((ext_vector_type(4)));

// round-to-nearest-even fp32 -> bf16 (bit pattern)
__device__ inline u16 f2bf(float f) {
    union { float f; u32 u; } v; v.f = f;
    u32 u = v.u;
    u32 r = (u + 0x7fffu + ((u >> 16) & 1u)) >> 16;
    return (u16)r;
}
__device__ inline float bf2f(u32 bits16) {
    union { u32 u; float f; } v; v.u = bits16 << 16;
    return v.f;
}

// async global->LDS, 16B per lane. LDS dest must be wave-uniform-base + lane*16.
__device__ inline void gl_lds16(const u16* g, u16* l) {
    __builtin_amdgcn_global_load_lds(
        (const __attribute__((address_space(1))) u32*)g,
        (__attribute__((address_space(3))) u32*)l, 16, 0, 0);
}

// ---------------------------------------------------------------------------
// prep_w: QT[h][i] = bf16(Q[i][h]); KwT[h][n] = bf16(Kw[n][h])
__global__ void prep_w(const float* __restrict__ Q, const float* __restrict__ Kw,
                       u16* __restrict__ QT, u16* __restrict__ KwT) {
    int idx = blockIdx.x * 256 + threadIdx.x;           // 0 .. 131071
    const float* src = (idx < 65536) ? Q : Kw;
    u16* dst = (idx < 65536) ? QT : KwT;
    int i = idx & 65535;
    int h = i >> 10;         // 0..63
    int n = i & 1023;        // 0..1023 (contiguous store)
    dst[h * 1024 + n] = f2bf(src[n * 64 + h]);
}

// prep_g: Gbt[j][i] = bf16(G[i][j]) (tiled transpose) + Grsum[i] = sum_j G[i][j]
__global__ void prep_g(const float* __restrict__ G, u16* __restrict__ Gbt,
                       float* __restrict__ Grsum) {
    __shared__ float tile[64][65];
    int i0 = blockIdx.y * 64, j0 = blockIdx.x * 64;
    int tx = threadIdx.x & 63, ty = threadIdx.x >> 6;   // ty 0..3
    for (int r = 0; r < 16; ++r) {
        int i = ty * 16 + r;
        tile[i][tx] = G[(size_t)(i0 + i) * 1024 + j0 + tx];
    }
    __syncthreads();
    for (int r = 0; r < 16; ++r) {
        int j = ty * 16 + r;
        Gbt[(size_t)(j0 + j) * 1024 + i0 + tx] = f2bf(tile[tx][j]);
    }
    if (ty == 0) {
        float sum = 0.f;
        for (int j = 0; j < 64; ++j) sum += tile[tx][j];
        atomicAdd(&Grsum[i0 + tx], sum);
    }
}

// prep_s: sb[n][b][i] = bf16(s[n][b][i]); sbT[b][i][n] = bf16(s[n][b][i])
__global__ void prep_s(const float* __restrict__ s, u16* __restrict__ sb,
                       u16* __restrict__ sbT) {
    __shared__ u16 tile[64][65];
    int b = blockIdx.z, n0 = blockIdx.y * 64, i0 = blockIdx.x * 64;
    int tx = threadIdx.x & 63, ty = threadIdx.x >> 6;
    for (int r = 0; r < 16; ++r) {
        int n = ty * 16 + r;
        size_t gi = (size_t)(n0 + n) * (BATCH * IN_DIM) + (size_t)b * IN_DIM + i0 + tx;
        u16 bv = f2bf(s[gi]);
        sb[gi] = bv;
        tile[n][tx] = bv;
    }
    __syncthreads();
    for (int r = 0; r < 16; ++r) {
        int i = ty * 16 + r;
        sbT[(size_t)b * (IN_DIM * N_DIM) + (size_t)(i0 + i) * N_DIM + n0 + tx] = tile[tx][i];
    }
}

// ---------------------------------------------------------------------------
// gemm_qkt: BM=128, BN=64, BK=32, K=1024. 4 waves x (32 x 64).
//   z <  16: q[b]  (1024x64) = S_b(sb, ld 16384) @ Q   (Bt = QT)
//   z >= 16: kt[b] (1024x64) = S_b^T(sbT, ld 1024) @ Kw (Bt = KwT)
__global__ __launch_bounds__(256) void gemm_qkt(
        const u16* __restrict__ sb, const u16* __restrict__ sbT,
        const u16* __restrict__ QT, const u16* __restrict__ KwT,
        u16* __restrict__ qws, u16* __restrict__ ktws) {
    int z = blockIdx.z, b = z & 15;
    const u16* A; size_t ldA; const u16* Bt; u16* out;
    if (z < 16) { A = sb  + (size_t)b * IN_DIM;          ldA = BATCH * IN_DIM; Bt = QT;  out = qws  + (size_t)b * (N_DIM * H_DIM); }
    else        { A = sbT + (size_t)b * (IN_DIM * N_DIM); ldA = N_DIM;         Bt = KwT; out = ktws + (size_t)b * (IN_DIM * H_DIM); }
    int m0 = blockIdx.x * 128;
    __shared__ u16 As[128 * 32];
    __shared__ u16 Bs[64 * 32];
    int t = threadIdx.x, lane = t & 63, w = t >> 6;
    f32x4 acc[2][4] = {};
    for (int k0 = 0; k0 < 1024; k0 += 32) {
        int r = t >> 2, c = (t & 3) * 8;
        gl_lds16(A + (size_t)(m0 + r) * ldA + k0 + c,      &As[r * 32 + c]);
        gl_lds16(A + (size_t)(m0 + r + 64) * ldA + k0 + c, &As[(r + 64) * 32 + c]);
        gl_lds16(Bt + (size_t)r * 1024 + k0 + c,           &Bs[r * 32 + c]);
        __syncthreads();
        int kh = (lane >> 4) * 8;
        bf16x8 af[2], bfr[4];
        for (int rt = 0; rt < 2; ++rt)
            af[rt] = *(const bf16x8*)&As[(w * 32 + rt * 16 + (lane & 15)) * 32 + kh];
        for (int ct = 0; ct < 4; ++ct)
            bfr[ct] = *(const bf16x8*)&Bs[(ct * 16 + (lane & 15)) * 32 + kh];
        for (int rt = 0; rt < 2; ++rt)
            for (int ct = 0; ct < 4; ++ct)
                acc[rt][ct] = __builtin_amdgcn_mfma_f32_16x16x32_bf16(af[rt], bfr[ct], acc[rt][ct], 0, 0, 0);
        __syncthreads();
    }
    for (int rt = 0; rt < 2; ++rt)
        for (int ct = 0; ct < 4; ++ct)
            for (int r = 0; r < 4; ++r) {
                int m = w * 32 + rt * 16 + (lane >> 4) * 4 + r;
                int n = ct * 16 + (lane & 15);
                out[(size_t)(m0 + m) * H_DIM + n] = f2bf(acc[rt][ct][r]);
            }
}

// gemm_score: per b: score(1024x1024) = q(1024x64) @ kt(1024x64)^T, K=64.
// epilogue: att = (score*0.125 + 1e-9)^2  (bf16)
__global__ __launch_bounds__(256) void gemm_score(
        const u16* __restrict__ qws, const u16* __restrict__ ktws,
        u16* __restrict__ att) {
    int b = blockIdx.z;
    const u16* A  = qws  + (size_t)b * (N_DIM * H_DIM);   // ld 64
    const u16* Bt = ktws + (size_t)b * (IN_DIM * H_DIM);  // ld 64
    int m0 = blockIdx.y * 128, n0 = blockIdx.x * 128;
    __shared__ u16 As[128 * 32];
    __shared__ u16 Bs[128 * 32];
    int t = threadIdx.x, lane = t & 63, w = t >> 6;
    int wm = (w >> 1) * 64, wn = (w & 1) * 64;
    f32x4 acc[4][4] = {};
    for (int k0 = 0; k0 < 64; k0 += 32) {
        int r = t >> 2, c = (t & 3) * 8;
        gl_lds16(A  + (size_t)(m0 + r) * 64 + k0 + c,      &As[r * 32 + c]);
        gl_lds16(A  + (size_t)(m0 + r + 64) * 64 + k0 + c, &As[(r + 64) * 32 + c]);
        gl_lds16(Bt + (size_t)(n0 + r) * 64 + k0 + c,      &Bs[r * 32 + c]);
        gl_lds16(Bt + (size_t)(n0 + r + 64) * 64 + k0 + c, &Bs[(r + 64) * 32 + c]);
        __syncthreads();
        int kh = (lane >> 4) * 8;
        bf16x8 af[4], bfr[4];
        for (int i = 0; i < 4; ++i)
            af[i] = *(const bf16x8*)&As[(wm + i * 16 + (lane & 15)) * 32 + kh];
        for (int j = 0; j < 4; ++j)
            bfr[j] = *(const bf16x8*)&Bs[(wn + j * 16 + (lane & 15)) * 32 + kh];
        for (int i = 0; i < 4; ++i)
            for (int j = 0; j < 4; ++j)
                acc[i][j] = __builtin_amdgcn_mfma_f32_16x16x32_bf16(af[i], bfr[j], acc[i][j], 0, 0, 0);
        __syncthreads();
    }
    for (int i = 0; i < 4; ++i)
        for (int j = 0; j < 4; ++j)
            for (int r = 0; r < 4; ++r) {
                int m = m0 + wm + i * 16 + (lane >> 4) * 4 + r;
                int n = n0 + wn + j * 16 + (lane & 15);
                float v = acc[i][j][r] * 0.125f + 1e-9f;   // 1/sqrt(64)
                v = v * v;
                att[(size_t)b * (N_DIM * IN_DIM) + (size_t)m * IN_DIM + n] = f2bf(v);
            }
}

// rowsum_k: rinv[b*1024+n] = 1 / (sum_i att[b][n][i]*Grsum[i] + 0.001)
__global__ void rowsum_k(const u16* __restrict__ att, const float* __restrict__ Grsum,
                         float* __restrict__ rinv) {
    int bn = blockIdx.x;
    const u16* row = att + (size_t)bn * 1024;
    int t = threadIdx.x;
    uint2 p = ((const uint2*)row)[t];        // 4 bf16
    float4 g = ((const float4*)Grsum)[t];    // 4 fp32
    float sum = bf2f(p.x & 0xffffu) * g.x + bf2f(p.x >> 16) * g.y
              + bf2f(p.y & 0xffffu) * g.z + bf2f(p.y >> 16) * g.w;
    for (int off = 32; off; off >>= 1) sum += __shfl_down(sum, off, 64);
    __shared__ float ws[4];
    if ((t & 63) == 0) ws[t >> 6] = sum;
    __syncthreads();
    if (t == 0) rinv[bn] = 1.0f / (ws[0] + ws[1] + ws[2] + ws[3] + 0.001f);
}

// gemm_big: per b: agg(1024x1024) = att(1024x1024) @ G, K=1024, Bt = Gbt (j,i).
// epilogue: out[n][b][j] = agg * rinv[b][n]   (fp32, direct transposed write)
__global__ __launch_bounds__(256) void gemm_big(
        const u16* __restrict__ att, const u16* __restrict__ Gbt,
        const float* __restrict__ rinv, float* __restrict__ out) {
    int b = blockIdx.z;
    const u16* A = att + (size_t)b * (N_DIM * IN_DIM);    // ld 1024
    int m0 = blockIdx.y * 128, n0 = blockIdx.x * 128;
    __shared__ u16 As[128 * 32];
    __shared__ u16 Bs[128 * 32];
    int t = threadIdx.x, lane = t & 63, w = t >> 6;
    int wm = (w >> 1) * 64, wn = (w & 1) * 64;
    f32x4 acc[4][4] = {};
    for (int k0 = 0; k0 < 1024; k0 += 32) {
        int r = t >> 2, c = (t & 3) * 8;
        gl_lds16(A   + (size_t)(m0 + r) * 1024 + k0 + c,      &As[r * 32 + c]);
        gl_lds16(A   + (size_t)(m0 + r + 64) * 1024 + k0 + c, &As[(r + 64) * 32 + c]);
        gl_lds16(Gbt + (size_t)(n0 + r) * 1024 + k0 + c,      &Bs[r * 32 + c]);
        gl_lds16(Gbt + (size_t)(n0 + r + 64) * 1024 + k0 + c, &Bs[(r + 64) * 32 + c]);
        __syncthreads();
        int kh = (lane >> 4) * 8;
        bf16x8 af[4], bfr[4];
        for (int i = 0; i < 4; ++i)
            af[i] = *(const bf16x8*)&As[(wm + i * 16 + (lane & 15)) * 32 + kh];
        for (int j = 0; j < 4; ++j)
            bfr[j] = *(const bf16x8*)&Bs[(wn + j * 16 + (lane & 15)) * 32 + kh];
        for (int i = 0; i < 4; ++i)
            for (int j = 0; j < 4; ++j)
                acc[i][j] = __builtin_amdgcn_mfma_f32_16x16x32_bf16(af[i], bfr[j], acc[i][j], 0, 0, 0);
        __syncthreads();
    }
    for (int i = 0; i < 4; ++i)
        for (int r = 0; r < 4; ++r) {
            int m = m0 + wm + i * 16 + (lane >> 4) * 4 + r;      // node index
            float rv = rinv[b * 1024 + m];
            for (int j = 0; j < 4; ++j) {
                int n = n0 + wn + j * 16 + (lane & 15);          // output j
                out[(size_t)m * (BATCH * IN_DIM) + (size_t)b * IN_DIM + n] = acc[i][j][r] * rv;
            }
        }
}

// ---------------------------------------------------------------------------
extern "C" void kernel_launch(void* const* d_in, const int* in_sizes, int n_in,
                              void* d_out, int out_size, void* d_ws, size_t ws_size,
                              hipStream_t stream) {
    const float* s  = (const float*)d_in[0];
    const float* G  = (const float*)d_in[1];
    const float* Q  = (const float*)d_in[2];
    const float* Kw = (const float*)d_in[3];
    float* out = (float*)d_out;
    char* ws = (char*)d_ws;

    u16*  sb    = (u16*)(ws);                                    // 32 MB (aliased by att later)
    u16*  sbT   = (u16*)(ws + (size_t)(32u << 20));              // 32 MB
    u16*  qws   = (u16*)(ws + (size_t)(64u << 20));              // 2 MB
    u16*  ktws  = (u16*)(ws + (size_t)(66u << 20));              // 2 MB
    u16*  Gbt   = (u16*)(ws + (size_t)(68u << 20));              // 2 MB
    u16*  QT    = (u16*)(ws + (size_t)(70u << 20));              // 128 KB
    u16*  KwT   = (u16*)(ws + (size_t)(70u << 20) + (128u << 10)); // 128 KB
    float* Grsum= (float*)(ws + (size_t)(70u << 20) + (256u << 10)); // 4 KB
    float* rinv = (float*)(ws + (size_t)(70u << 20) + (260u << 10)); // 64 KB
    u16*  att   = sb;   // sb dead after gemm_qkt; att (32 MB) reuses it

    hipMemsetAsync(Grsum, 0, 1024 * sizeof(float), stream);
    prep_w<<<512, 256, 0, stream>>>(Q, Kw, QT, KwT);
    prep_g<<<dim3(16, 16), 256, 0, stream>>>(G, Gbt, Grsum);
    prep_s<<<dim3(16, 16, 16), 256, 0, stream>>>(s, sb, sbT);
    gemm_qkt<<<dim3(8, 1, 32), 256, 0, stream>>>(sb, sbT, QT, KwT, qws, ktws);
    gemm_score<<<dim3(8, 8, 16), 256, 0, stream>>>(qws, ktws, att);
    rowsum_k<<<16384, 256, 0, stream>>>(att, Grsum, rinv);
    gemm_big<<<dim3(8, 8, 16), 256, 0, stream>>>(att, Gbt, rinv, out);
}

// Round 2
// 230.014 us; speedup vs baseline: 1.0370x; 1.0370x over previous
//
#include <hip/hip_runtime.h>
#include <stdint.h>

typedef unsigned short u16;
typedef unsigned int   u32;

#define N_DIM  1024
#define IN_DIM 1024
#define H_DIM  64
#define BATCH  16

typedef __bf16 bf16x8 __attribute__((ext_vector_type(8)));
typedef float  f32x4  __attribute__((ext_vector_type(4)));

// round-to-nearest-even fp32 -> bf16 (bit pattern)
__device__ inline u16 f2bf(float f) {
    union { float f; u32 u; } v; v.f = f;
    u32 u = v.u;
    return (u16)((u + 0x7fffu + ((u >> 16) & 1u)) >> 16);
}
__device__ inline u32 pack2(float a, float b) {
    return (u32)f2bf(a) | ((u32)f2bf(b) << 16);
}

// async global->LDS, 16B per lane. LDS dest must be wave-uniform base + lane*16.
__device__ inline void gl_lds16(const u16* g, u16* l) {
    __builtin_amdgcn_global_load_lds(
        (const __attribute__((address_space(1))) u32*)g,
        (__attribute__((address_space(3))) u32*)l, 16, 0, 0);
}

// ---------------------------------------------------------------------------
// prep_w: QT[h][i] = bf16(Q[i][h]); KwT[h][n] = bf16(Kw[n][h])
__global__ void prep_w(const float* __restrict__ Q, const float* __restrict__ Kw,
                       u16* __restrict__ QT, u16* __restrict__ KwT) {
    int idx = blockIdx.x * 256 + threadIdx.x;           // 0 .. 131071
    const float* src = (idx < 65536) ? Q : Kw;
    u16* dst = (idx < 65536) ? QT : KwT;
    int i = idx & 65535;
    int h = i >> 10;         // 0..63
    int n = i & 1023;        // 0..1023 (contiguous store)
    dst[h * 1024 + n] = f2bf(src[n * 64 + h]);
}

// prep_g: Gbt[j][i] = bf16(G[i][j]) (tiled transpose) + Grsum[i] = sum_j G[i][j]
__global__ void prep_g(const float* __restrict__ G, u16* __restrict__ Gbt,
                       float* __restrict__ Grsum) {
    __shared__ float tile[64][65];
    int i0 = blockIdx.y * 64, j0 = blockIdx.x * 64;
    int tx = threadIdx.x & 63, ty = threadIdx.x >> 6;   // ty 0..3
    for (int r = 0; r < 16; ++r) {
        int i = ty * 16 + r;
        tile[i][tx] = G[(size_t)(i0 + i) * 1024 + j0 + tx];
    }
    __syncthreads();
    for (int r = 0; r < 16; ++r) {
        int j = ty * 16 + r;
        Gbt[(size_t)(j0 + j) * 1024 + i0 + tx] = f2bf(tile[tx][j]);
    }
    if (ty == 0) {
        float sum = 0.f;
        for (int j = 0; j < 64; ++j) sum += tile[tx][j];
        atomicAdd(&Grsum[i0 + tx], sum);
    }
}

// ---------------------------------------------------------------------------
// gemm_qkt: reads fp32 s directly (no bf16 prep pass).
//   z <  16: q[b]  (1024x64) = S_b @ Qw      A[m=node][k=i] : cast-stage
//   z >= 16: kt[b] (1024x64) = S_b^T @ Kw    A[m=i][k=node] : transpose-stage
// BM=128, BN=64, BK=32. Padded LDS (stride 40) since staging is through VGPRs.
__global__ __launch_bounds__(256) void gemm_qkt(
        const float* __restrict__ s, const u16* __restrict__ QT,
        const u16* __restrict__ KwT, u16* __restrict__ qws, u16* __restrict__ ktws) {
    int z = blockIdx.z; int b = z & 15; bool isq = (z < 16);
    int m0 = blockIdx.x * 128;
    __shared__ __align__(16) u16 As[128 * 40];
    __shared__ __align__(16) u16 Bs[64 * 40];
    const u16* Bt = isq ? QT : KwT;
    u16* outp = (isq ? qws : ktws) + (size_t)b * 65536;
    int t = threadIdx.x, lane = t & 63, w = t >> 6, quad = lane >> 4, l15 = lane & 15;
    f32x4 acc[2][4] = {};
    for (int k0 = 0; k0 < 1024; k0 += 32) {
        {   // stage B tile 64x32 (bf16 global, padded write)
            int h = t >> 2, c = (t & 3) * 8;
            uint4 v = *(const uint4*)&Bt[(size_t)h * 1024 + k0 + c];
            *(uint4*)&Bs[h * 40 + c] = v;
        }
        if (isq) {          // A tile 128x32 from s rows, cast fp32->bf16
            int r = t >> 1, c = (t & 1) * 16;
            const float* src = s + (size_t)(m0 + r) * (BATCH * IN_DIM) + (size_t)b * IN_DIM + k0 + c;
            float4 f0 = ((const float4*)src)[0];
            float4 f1 = ((const float4*)src)[1];
            float4 f2 = ((const float4*)src)[2];
            float4 f3 = ((const float4*)src)[3];
            uint4 w0 = { pack2(f0.x,f0.y), pack2(f0.z,f0.w), pack2(f1.x,f1.y), pack2(f1.z,f1.w) };
            uint4 w1 = { pack2(f2.x,f2.y), pack2(f2.z,f2.w), pack2(f3.x,f3.y), pack2(f3.z,f3.w) };
            *(uint4*)&As[r * 40 + c]     = w0;
            *(uint4*)&As[r * 40 + c + 8] = w1;
        } else {            // A tile 128(i) x 32(n): transpose of s rows
            int nr = t >> 3, icb = (t & 7) * 4;
            const float* src = s + (size_t)(k0 + nr) * (BATCH * IN_DIM) + (size_t)b * IN_DIM + m0;
            for (int j3 = 0; j3 < 4; ++j3) {
                float4 f = *(const float4*)&src[icb + 32 * j3];
                As[(icb + 32*j3 + 0) * 40 + nr] = f2bf(f.x);
                As[(icb + 32*j3 + 1) * 40 + nr] = f2bf(f.y);
                As[(icb + 32*j3 + 2) * 40 + nr] = f2bf(f.z);
                As[(icb + 32*j3 + 3) * 40 + nr] = f2bf(f.w);
            }
        }
        __syncthreads();
        int kh = quad * 8;
        bf16x8 af[2], bfr[4];
        for (int rt = 0; rt < 2; ++rt) af[rt] = *(const bf16x8*)&As[(w*32 + rt*16 + l15) * 40 + kh];
        for (int ct = 0; ct < 4; ++ct) bfr[ct] = *(const bf16x8*)&Bs[(ct*16 + l15) * 40 + kh];
        for (int rt = 0; rt < 2; ++rt)
            for (int ct = 0; ct < 4; ++ct)
                acc[rt][ct] = __builtin_amdgcn_mfma_f32_16x16x32_bf16(af[rt], bfr[ct], acc[rt][ct], 0, 0, 0);
        __syncthreads();
    }
    for (int rt = 0; rt < 2; ++rt)
        for (int ct = 0; ct < 4; ++ct)
            for (int r = 0; r < 4; ++r) {
                int m = w * 32 + rt * 16 + quad * 4 + r;
                int n = ct * 16 + l15;
                outp[(size_t)(m0 + m) * 64 + n] = f2bf(acc[rt][ct][r]);
            }
}

// ---------------------------------------------------------------------------
// gemm_fused: per (b, m-tile 128, n-tile 128):
//   K-loop over i (32/step): score chunk S^T(32i x 128m) = kt_chunk @ q^T (MFMA),
//   square(+1e-9), accumulate rowsum via Grsum identity, pack bf16 -> As (padded),
//   then agg k-step: acc += As(128x32) @ Gbt-chunk. Epilogue: scale by
//   1/(rowsum+1e-3), write transposed (n,B,j) fp32 output. att never hits HBM.
__global__ __launch_bounds__(256) void gemm_fused(
        const u16* __restrict__ qws, const u16* __restrict__ ktws,
        const u16* __restrict__ Gbt, const float* __restrict__ Grsum,
        float* __restrict__ out) {
    int b = blockIdx.z;
    int n0 = blockIdx.x * 128, m0 = blockIdx.y * 128;
    const u16* qb = qws  + (size_t)b * 65536;
    const u16* kb = ktws + (size_t)b * 65536;
    __shared__ __align__(16) u16 As[128 * 40];       // score->agg buffer, padded
    __shared__ __align__(16) u16 Bs[2][128 * 32];    // Gbt staging (gl_lds, dbuf)
    __shared__ __align__(16) u16 ktc[2][32 * 72];    // kt chunk, padded, dbuf
    __shared__ __align__(16) float Grs[1024];
    __shared__ float rs[128];
    int t = threadIdx.x, lane = t & 63, w = t >> 6, quad = lane >> 4, l15 = lane & 15;
    int ti = w & 1;                 // score i-subtile
    int wm = (w >> 1) * 64, wn = (w & 1) * 64;   // agg 2x2 wave tiling

    ((float4*)Grs)[t] = ((const float4*)Grsum)[t];
    if (t < 128) rs[t] = 0.f;

    // K-invariant q B-frags: B[k=h][col=m], 8 contiguous h per lane
    bf16x8 qf[4][2];
    for (int j = 0; j < 4; ++j)
        for (int kick = 0; kick < 2; ++kick)
            qf[j][kick] = *(const bf16x8*)&qb[(size_t)(m0 + wm + j*16 + l15) * 64 + kick*32 + quad*8];

    // iter-0 staging
    int br = t >> 2, bc = (t & 3) * 8;
    gl_lds16(Gbt + (size_t)(n0 + br) * 1024 + bc,      &Bs[0][br * 32 + bc]);
    gl_lds16(Gbt + (size_t)(n0 + br + 64) * 1024 + bc, &Bs[0][(br + 64) * 32 + bc]);
    int ir = t >> 3, ch = (t & 7) * 8;
    uint4 kreg = *(const uint4*)&kb[(size_t)ir * 64 + ch];

    f32x4 acc[4][4] = {};
    float partial[4] = {0.f, 0.f, 0.f, 0.f};

    for (int kk = 0; kk < 32; ++kk) {
        int buf = kk & 1;
        *(uint4*)&ktc[buf][ir * 72 + ch] = kreg;
        __syncthreads();                       // barrier1: Bs[buf] + ktc[buf] ready
        // ---- score: S^T[i][m] for i-subtile ti, m in wave's 64-half
        f32x4 sacc[4] = {};
        for (int kick = 0; kick < 2; ++kick) {
            bf16x8 ktf = *(const bf16x8*)&ktc[buf][(ti*16 + l15) * 72 + kick*32 + quad*8];
            for (int j = 0; j < 4; ++j)
                sacc[j] = __builtin_amdgcn_mfma_f32_16x16x32_bf16(ktf, qf[j][kick], sacc[j], 0, 0, 0);
        }
        if (kk < 31)
            kreg = *(const uint4*)&kb[(size_t)((kk + 1) * 32 + ir) * 64 + ch];
        // ---- epilogue: square, rowsum partial, pack to As
        float4 g = *(const float4*)&Grs[kk * 32 + ti * 16 + quad * 4];
        for (int j = 0; j < 4; ++j) {
            float v0 = sacc[j][0] * 0.125f + 1e-9f; v0 *= v0;
            float v1 = sacc[j][1] * 0.125f + 1e-9f; v1 *= v1;
            float v2 = sacc[j][2] * 0.125f + 1e-9f; v2 *= v2;
            float v3 = sacc[j][3] * 0.125f + 1e-9f; v3 *= v3;
            partial[j] += v0 * g.x + v1 * g.y + v2 * g.z + v3 * g.w;
            uint2 pk = { pack2(v0, v1), pack2(v2, v3) };
            *(uint2*)&As[(wm + j*16 + l15) * 40 + ti*16 + quad*4] = pk;
        }
        __syncthreads();                       // barrier2: As ready
        if (kk < 31) {                         // prefetch next Gbt chunk (in flight across agg)
            gl_lds16(Gbt + (size_t)(n0 + br) * 1024 + (kk+1)*32 + bc,      &Bs[buf^1][br * 32 + bc]);
            gl_lds16(Gbt + (size_t)(n0 + br + 64) * 1024 + (kk+1)*32 + bc, &Bs[buf^1][(br + 64) * 32 + bc]);
        }
        // ---- agg k-step
        int kh = quad * 8;
        bf16x8 af[4], bfr[4];
        for (int i = 0; i < 4; ++i) af[i]  = *(const bf16x8*)&As[(wm + i*16 + l15) * 40 + kh];
        for (int j = 0; j < 4; ++j) bfr[j] = *(const bf16x8*)&Bs[buf][(wn + j*16 + l15) * 32 + kh];
        for (int i = 0; i < 4; ++i)
            for (int j = 0; j < 4; ++j)
                acc[i][j] = __builtin_amdgcn_mfma_f32_16x16x32_bf16(af[i], bfr[j], acc[i][j], 0, 0, 0);
    }

    // rowsum: reduce quads (same m, different i-subsets), then combine waves via LDS
    for (int j = 0; j < 4; ++j) {
        partial[j] += __shfl_xor(partial[j], 16, 64);
        partial[j] += __shfl_xor(partial[j], 32, 64);
    }
    if (quad == 0)
        for (int j = 0; j < 4; ++j) atomicAdd(&rs[wm + j*16 + l15], partial[j]);
    __syncthreads();
    if (t < 128) rs[t] = 1.0f / (rs[t] + 0.001f);
    __syncthreads();

    for (int i = 0; i < 4; ++i) {
        float4 rv = *(const float4*)&rs[wm + i * 16 + quad * 4];
        float rva[4] = { rv.x, rv.y, rv.z, rv.w };
        for (int r = 0; r < 4; ++r) {
            int m = m0 + wm + i * 16 + quad * 4 + r;
            float* orow = out + (size_t)m * (BATCH * IN_DIM) + (size_t)b * IN_DIM + n0;
            for (int j = 0; j < 4; ++j)
                orow[wn + j * 16 + l15] = acc[i][j][r] * rva[r];
        }
    }
}

// ---------------------------------------------------------------------------
extern "C" void kernel_launch(void* const* d_in, const int* in_sizes, int n_in,
                              void* d_out, int out_size, void* d_ws, size_t ws_size,
                              hipStream_t stream) {
    const float* s  = (const float*)d_in[0];
    const float* G  = (const float*)d_in[1];
    const float* Q  = (const float*)d_in[2];
    const float* Kw = (const float*)d_in[3];
    float* out = (float*)d_out;
    char* ws = (char*)d_ws;

    u16*   qws   = (u16*)(ws);                                   // 2 MB
    u16*   ktws  = (u16*)(ws + (size_t)(2u << 20));              // 2 MB
    u16*   Gbt   = (u16*)(ws + (size_t)(4u << 20));              // 2 MB
    u16*   QT    = (u16*)(ws + (size_t)(6u << 20));              // 128 KB
    u16*   KwT   = (u16*)(ws + (size_t)(6u << 20) + (128u << 10)); // 128 KB
    float* Grsum = (float*)(ws + (size_t)(6u << 20) + (256u << 10)); // 4 KB

    hipMemsetAsync(Grsum, 0, 1024 * sizeof(float), stream);
    prep_w<<<512, 256, 0, stream>>>(Q, Kw, QT, KwT);
    prep_g<<<dim3(16, 16), 256, 0, stream>>>(G, Gbt, Grsum);
    gemm_qkt<<<dim3(8, 1, 32), 256, 0, stream>>>(s, QT, KwT, qws, ktws);
    gemm_fused<<<dim3(8, 8, 16), 256, 0, stream>>>(qws, ktws, Gbt, Grsum, out);
}

// Round 3
// 229.792 us; speedup vs baseline: 1.0380x; 1.0010x over previous
//
#include <hip/hip_runtime.h>
#include <hip/hip_bf16.h>
#include <stdint.h>

typedef unsigned short u16;
typedef unsigned int   u32;

#define N_DIM  1024
#define IN_DIM 1024
#define H_DIM  64
#define BATCH  16

typedef __bf16 bf16x8 __attribute__((ext_vector_type(8)));
typedef float  f32x4  __attribute__((ext_vector_type(4)));

// round-to-nearest-even fp32 -> bf16 (bit pattern)
__device__ inline u16 f2bf(float f) {
    union { float f; u32 u; } v; v.f = f;
    u32 u = v.u;
    return (u16)((u + 0x7fffu + ((u >> 16) & 1u)) >> 16);
}
// packed pair: maps to v_cvt_pk_bf16_f32 on gfx950 if the header supports it
__device__ inline u32 pack2(float a, float b) {
    __hip_bfloat162 h = __float22bfloat162_rn(float2{a, b});
    union { __hip_bfloat162 h; u32 u; } cv; cv.h = h; return cv.u;
}

// async global->LDS, 16B per lane. LDS dest must be wave-uniform base + lane*16.
__device__ inline void gl_lds16(const u16* g, u16* l) {
    __builtin_amdgcn_global_load_lds(
        (const __attribute__((address_space(1))) u32*)g,
        (__attribute__((address_space(3))) u32*)l, 16, 0, 0);
}

// ---------------------------------------------------------------------------
// prep_w: QT[h][i] = bf16(Q[i][h]); KwT[h][n] = bf16(Kw[n][h])
__global__ void prep_w(const float* __restrict__ Q, const float* __restrict__ Kw,
                       u16* __restrict__ QT, u16* __restrict__ KwT) {
    int idx = blockIdx.x * 256 + threadIdx.x;           // 0 .. 131071
    const float* src = (idx < 65536) ? Q : Kw;
    u16* dst = (idx < 65536) ? QT : KwT;
    int i = idx & 65535;
    int h = i >> 10;         // 0..63
    int n = i & 1023;        // 0..1023 (contiguous store)
    dst[h * 1024 + n] = f2bf(src[n * 64 + h]);
}

// prep_g: Gbt[j][i] = bf16(G[i][j]) (tiled transpose) + Grsum[i] = sum_j G[i][j]
__global__ void prep_g(const float* __restrict__ G, u16* __restrict__ Gbt,
                       float* __restrict__ Grsum) {
    __shared__ float tile[64][65];
    int i0 = blockIdx.y * 64, j0 = blockIdx.x * 64;
    int tx = threadIdx.x & 63, ty = threadIdx.x >> 6;   // ty 0..3
    for (int r = 0; r < 16; ++r) {
        int i = ty * 16 + r;
        tile[i][tx] = G[(size_t)(i0 + i) * 1024 + j0 + tx];
    }
    __syncthreads();
    for (int r = 0; r < 16; ++r) {
        int j = ty * 16 + r;
        Gbt[(size_t)(j0 + j) * 1024 + i0 + tx] = f2bf(tile[tx][j]);
    }
    if (ty == 0) {
        float sum = 0.f;
        for (int j = 0; j < 64; ++j) sum += tile[tx][j];
        atomicAdd(&Grsum[i0 + tx], sum);
    }
}

// ---------------------------------------------------------------------------
// gemm_qkt (split-K=4): reads fp32 s directly. Each block does K=256.
//   z <  16: q[b]  partial = S_b chunk @ Qw      A[m=node][k=i] : cast-stage
//   z >= 16: kt[b] partial = S_b^T chunk @ Kw    A[m=i][k=node] : transpose-stage
// Output: fp32 partials part[ks][z][m*64+h], reduced by reduce_qkt.
__global__ __launch_bounds__(256) void gemm_qkt(
        const float* __restrict__ s, const u16* __restrict__ QT,
        const u16* __restrict__ KwT, float* __restrict__ part) {
    int z = blockIdx.z; int b = z & 15; bool isq = (z < 16);
    int ks = blockIdx.y;                 // 0..3, K-range [ks*256, ks*256+256)
    int m0 = blockIdx.x * 128;
    __shared__ __align__(16) u16 As[128 * 40];
    __shared__ __align__(16) u16 Bs[64 * 40];
    const u16* Bt = isq ? QT : KwT;
    float* outp = part + (size_t)ks * 2097152 + (size_t)z * 65536;
    int t = threadIdx.x, lane = t & 63, w = t >> 6, quad = lane >> 4, l15 = lane & 15;
    f32x4 acc[2][4] = {};
    for (int kk = 0; kk < 8; ++kk) {
        int k0 = ks * 256 + kk * 32;
        {   // stage B tile 64x32 (bf16 global, padded write)
            int h = t >> 2, c = (t & 3) * 8;
            uint4 v = *(const uint4*)&Bt[(size_t)h * 1024 + k0 + c];
            *(uint4*)&Bs[h * 40 + c] = v;
        }
        if (isq) {          // A tile 128x32 from s rows, cast fp32->bf16
            int r = t >> 1, c = (t & 1) * 16;
            const float* src = s + (size_t)(m0 + r) * (BATCH * IN_DIM) + (size_t)b * IN_DIM + k0 + c;
            float4 f0 = ((const float4*)src)[0];
            float4 f1 = ((const float4*)src)[1];
            float4 f2 = ((const float4*)src)[2];
            float4 f3 = ((const float4*)src)[3];
            uint4 w0 = { pack2(f0.x,f0.y), pack2(f0.z,f0.w), pack2(f1.x,f1.y), pack2(f1.z,f1.w) };
            uint4 w1 = { pack2(f2.x,f2.y), pack2(f2.z,f2.w), pack2(f3.x,f3.y), pack2(f3.z,f3.w) };
            *(uint4*)&As[r * 40 + c]     = w0;
            *(uint4*)&As[r * 40 + c + 8] = w1;
        } else {            // A tile 128(i) x 32(n): transpose of s rows
            int nr = t >> 3, icb = (t & 7) * 4;
            const float* src = s + (size_t)(k0 + nr) * (BATCH * IN_DIM) + (size_t)b * IN_DIM + m0;
            for (int j3 = 0; j3 < 4; ++j3) {
                float4 f = *(const float4*)&src[icb + 32 * j3];
                As[(icb + 32*j3 + 0) * 40 + nr] = f2bf(f.x);
                As[(icb + 32*j3 + 1) * 40 + nr] = f2bf(f.y);
                As[(icb + 32*j3 + 2) * 40 + nr] = f2bf(f.z);
                As[(icb + 32*j3 + 3) * 40 + nr] = f2bf(f.w);
            }
        }
        __syncthreads();
        int kh = quad * 8;
        bf16x8 af[2], bfr[4];
        for (int rt = 0; rt < 2; ++rt) af[rt] = *(const bf16x8*)&As[(w*32 + rt*16 + l15) * 40 + kh];
        for (int ct = 0; ct < 4; ++ct) bfr[ct] = *(const bf16x8*)&Bs[(ct*16 + l15) * 40 + kh];
        for (int rt = 0; rt < 2; ++rt)
            for (int ct = 0; ct < 4; ++ct)
                acc[rt][ct] = __builtin_amdgcn_mfma_f32_16x16x32_bf16(af[rt], bfr[ct], acc[rt][ct], 0, 0, 0);
        __syncthreads();
    }
    for (int rt = 0; rt < 2; ++rt)
        for (int ct = 0; ct < 4; ++ct)
            for (int r = 0; r < 4; ++r) {
                int m = w * 32 + rt * 16 + quad * 4 + r;
                int n = ct * 16 + l15;
                outp[(size_t)(m0 + m) * 64 + n] = acc[rt][ct][r];
            }
}

// reduce_qkt: qkt_out[id(4 bf16)] = bf16(sum_ks part[ks][id(4 f32)])
// part: [4][2M floats]; qkt_out: 4M bf16 (q for b=0..15, then kt for b=0..15)
__global__ void reduce_qkt(const float* __restrict__ part, u16* __restrict__ qkt_out) {
    int id = blockIdx.x * 256 + threadIdx.x;     // 0 .. 524287 (float4 index)
    const float4* p = (const float4*)part;
    float4 a = p[id];
    float4 b1 = p[id + 524288];
    float4 c = p[id + 1048576];
    float4 d = p[id + 1572864];
    a.x += b1.x + c.x + d.x; a.y += b1.y + c.y + d.y;
    a.z += b1.z + c.z + d.z; a.w += b1.w + c.w + d.w;
    uint2 pk = { pack2(a.x, a.y), pack2(a.z, a.w) };
    ((uint2*)qkt_out)[id] = pk;
}

// ---------------------------------------------------------------------------
// gemm_fused: per (b, m-tile 128, n-tile 128):
//   K-loop over i (32/step): score chunk S^T(32i x 128m) = kt_chunk @ q^T (MFMA),
//   square(+1e-9), accumulate rowsum via Grsum identity, pack bf16 -> As (padded),
//   then agg k-step: acc += As(128x32) @ Gbt-chunk. Epilogue: scale by
//   1/(rowsum+1e-3), write transposed (n,B,j) fp32 output. att never hits HBM.
// Bs is XOR-swizzled (gl_lds can't pad): LDS[r][c] = Gbt[r][c ^ ((r&3)*8)].
__global__ __launch_bounds__(256) void gemm_fused(
        const u16* __restrict__ qws, const u16* __restrict__ ktws,
        const u16* __restrict__ Gbt, const float* __restrict__ Grsum,
        float* __restrict__ out) {
    int b = blockIdx.z;
    int n0 = blockIdx.x * 128, m0 = blockIdx.y * 128;
    const u16* qb = qws  + (size_t)b * 65536;
    const u16* kb = ktws + (size_t)b * 65536;
    __shared__ __align__(16) u16 As[128 * 40];       // score->agg buffer, padded
    __shared__ __align__(16) u16 Bs[2][128 * 32];    // Gbt staging (gl_lds, swizzled, dbuf)
    __shared__ __align__(16) u16 ktc[32 * 72];       // kt chunk, padded, single buf
    __shared__ __align__(16) float Grs[1024];
    __shared__ float rs[128];
    int t = threadIdx.x, lane = t & 63, w = t >> 6, quad = lane >> 4, l15 = lane & 15;
    int ti = w & 1;                 // score i-subtile
    int wm = (w >> 1) * 64, wn = (w & 1) * 64;   // agg 2x2 wave tiling

    ((float4*)Grs)[t] = ((const float4*)Grsum)[t];
    if (t < 128) rs[t] = 0.f;

    // K-invariant q B-frags: B[k=h][col=m], 8 contiguous h per lane
    bf16x8 qf[4][2];
    for (int j = 0; j < 4; ++j)
        for (int kick = 0; kick < 2; ++kick)
            qf[j][kick] = *(const bf16x8*)&qb[(size_t)(m0 + wm + j*16 + l15) * 64 + kick*32 + quad*8];

    // iter-0 staging (swizzled global column per lane)
    int br = t >> 2, bc = (t & 3) * 8;
    int bsw = (br & 3) * 8;          // XOR swizzle for this lane's rows
    gl_lds16(Gbt + (size_t)(n0 + br) * 1024 + (bc ^ bsw),      &Bs[0][br * 32 + bc]);
    gl_lds16(Gbt + (size_t)(n0 + br + 64) * 1024 + (bc ^ bsw), &Bs[0][(br + 64) * 32 + bc]);
    int ir = t >> 3, ch = (t & 7) * 8;
    uint4 kreg = *(const uint4*)&kb[(size_t)ir * 64 + ch];

    f32x4 acc[4][4] = {};
    float partial[4] = {0.f, 0.f, 0.f, 0.f};

    for (int kk = 0; kk < 32; ++kk) {
        int buf = kk & 1;
        *(uint4*)&ktc[ir * 72 + ch] = kreg;        // single buf: safe, prev reads done pre-barrier2
        __syncthreads();                           // barrier1: Bs[buf] + ktc ready
        // ---- score: S^T[i][m] for i-subtile ti, m in wave's 64-half
        f32x4 sacc[4] = {};
        for (int kick = 0; kick < 2; ++kick) {
            bf16x8 ktf = *(const bf16x8*)&ktc[(ti*16 + l15) * 72 + kick*32 + quad*8];
            for (int j = 0; j < 4; ++j)
                sacc[j] = __builtin_amdgcn_mfma_f32_16x16x32_bf16(ktf, qf[j][kick], sacc[j], 0, 0, 0);
        }
        if (kk < 31)
            kreg = *(const uint4*)&kb[(size_t)((kk + 1) * 32 + ir) * 64 + ch];
        // ---- epilogue: square, rowsum partial, pack to As
        float4 g = *(const float4*)&Grs[kk * 32 + ti * 16 + quad * 4];
        for (int j = 0; j < 4; ++j) {
            float v0 = sacc[j][0] * 0.125f + 1e-9f; v0 *= v0;
            float v1 = sacc[j][1] * 0.125f + 1e-9f; v1 *= v1;
            float v2 = sacc[j][2] * 0.125f + 1e-9f; v2 *= v2;
            float v3 = sacc[j][3] * 0.125f + 1e-9f; v3 *= v3;
            partial[j] += v0 * g.x + v1 * g.y + v2 * g.z + v3 * g.w;
            uint2 pk = { pack2(v0, v1), pack2(v2, v3) };
            *(uint2*)&As[(wm + j*16 + l15) * 40 + ti*16 + quad*4] = pk;
        }
        __syncthreads();                           // barrier2: As ready
        if (kk < 31) {                             // prefetch next Gbt chunk (swizzled)
            gl_lds16(Gbt + (size_t)(n0 + br) * 1024 + (kk+1)*32 + (bc ^ bsw),      &Bs[buf^1][br * 32 + bc]);
            gl_lds16(Gbt + (size_t)(n0 + br + 64) * 1024 + (kk+1)*32 + (bc ^ bsw), &Bs[buf^1][(br + 64) * 32 + bc]);
        }
        // ---- agg k-step
        int kh = quad * 8;
        bf16x8 af[4], bfr[4];
        for (int i = 0; i < 4; ++i) af[i]  = *(const bf16x8*)&As[(wm + i*16 + l15) * 40 + kh];
        for (int j = 0; j < 4; ++j) {
            int row = wn + j*16 + l15;
            bfr[j] = *(const bf16x8*)&Bs[buf][row * 32 + (kh ^ ((row & 3) * 8))];
        }
        for (int i = 0; i < 4; ++i)
            for (int j = 0; j < 4; ++j)
                acc[i][j] = __builtin_amdgcn_mfma_f32_16x16x32_bf16(af[i], bfr[j], acc[i][j], 0, 0, 0);
    }

    // rowsum: reduce quads (same m, different i-subsets), then combine waves via LDS
    for (int j = 0; j < 4; ++j) {
        partial[j] += __shfl_xor(partial[j], 16, 64);
        partial[j] += __shfl_xor(partial[j], 32, 64);
    }
    if (quad == 0)
        for (int j = 0; j < 4; ++j) atomicAdd(&rs[wm + j*16 + l15], partial[j]);
    __syncthreads();
    if (t < 128) rs[t] = 1.0f / (rs[t] + 0.001f);
    __syncthreads();

    for (int i = 0; i < 4; ++i) {
        float4 rv = *(const float4*)&rs[wm + i * 16 + quad * 4];
        float rva[4] = { rv.x, rv.y, rv.z, rv.w };
        for (int r = 0; r < 4; ++r) {
            int m = m0 + wm + i * 16 + quad * 4 + r;
            float* orow = out + (size_t)m * (BATCH * IN_DIM) + (size_t)b * IN_DIM + n0;
            for (int j = 0; j < 4; ++j)
                orow[wn + j * 16 + l15] = acc[i][j][r] * rva[r];
        }
    }
}

// ---------------------------------------------------------------------------
extern "C" void kernel_launch(void* const* d_in, const int* in_sizes, int n_in,
                              void* d_out, int out_size, void* d_ws, size_t ws_size,
                              hipStream_t stream) {
    const float* s  = (const float*)d_in[0];
    const float* G  = (const float*)d_in[1];
    const float* Q  = (const float*)d_in[2];
    const float* Kw = (const float*)d_in[3];
    float* out = (float*)d_out;
    char* ws = (char*)d_ws;

    float* part  = (float*)(ws);                                  // 32 MB (4 x 8 MB split-K partials)
    u16*   qws   = (u16*)(ws + (size_t)(32u << 20));              // 4 MB (q 2MB | kt 2MB)
    u16*   ktws  = qws + (size_t)16 * 65536;
    u16*   Gbt   = (u16*)(ws + (size_t)(36u << 20));              // 2 MB
    u16*   QT    = (u16*)(ws + (size_t)(38u << 20));              // 128 KB
    u16*   KwT   = (u16*)(ws + (size_t)(38u << 20) + (128u << 10)); // 128 KB
    float* Grsum = (float*)(ws + (size_t)(38u << 20) + (256u << 10)); // 4 KB

    hipMemsetAsync(Grsum, 0, 1024 * sizeof(float), stream);
    prep_w<<<512, 256, 0, stream>>>(Q, Kw, QT, KwT);
    prep_g<<<dim3(16, 16), 256, 0, stream>>>(G, Gbt, Grsum);
    gemm_qkt<<<dim3(8, 4, 32), 256, 0, stream>>>(s, QT, KwT, part);
    reduce_qkt<<<2048, 256, 0, stream>>>(part, qws);
    gemm_fused<<<dim3(8, 8, 16), 256, 0, stream>>>(qws, ktws, Gbt, Grsum, out);
}

// Round 4
// 193.360 us; speedup vs baseline: 1.2336x; 1.1884x over previous
//
#include <hip/hip_runtime.h>
#include <hip/hip_bf16.h>
#include <stdint.h>

typedef unsigned short u16;
typedef unsigned int   u32;

#define N_DIM  1024
#define IN_DIM 1024
#define H_DIM  64
#define BATCH  16

typedef __bf16 bf16x8 __attribute__((ext_vector_type(8)));
typedef float  f32x4  __attribute__((ext_vector_type(4)));

// round-to-nearest-even fp32 -> bf16 (bit pattern)
__device__ inline u16 f2bf(float f) {
    union { float f; u32 u; } v; v.f = f;
    u32 u = v.u;
    return (u16)((u + 0x7fffu + ((u >> 16) & 1u)) >> 16);
}
// packed pair: v_cvt_pk_bf16_f32 when available
__device__ inline u32 pack2(float a, float b) {
    __hip_bfloat162 h = __float22bfloat162_rn(float2{a, b});
    union { __hip_bfloat162 h; u32 u; } cv; cv.h = h; return cv.u;
}

// async global->LDS, 16B per lane. LDS dest must be wave-uniform base + lane*16.
__device__ inline void gl_lds16(const u16* g, u16* l) {
    __builtin_amdgcn_global_load_lds(
        (const __attribute__((address_space(1))) u32*)g,
        (__attribute__((address_space(3))) u32*)l, 16, 0, 0);
}

// ---------------------------------------------------------------------------
// prep_w: QT[h][i] = bf16(Q[i][h]); KwT[h][n] = bf16(Kw[n][h])
__global__ void prep_w(const float* __restrict__ Q, const float* __restrict__ Kw,
                       u16* __restrict__ QT, u16* __restrict__ KwT) {
    int idx = blockIdx.x * 256 + threadIdx.x;           // 0 .. 131071
    const float* src = (idx < 65536) ? Q : Kw;
    u16* dst = (idx < 65536) ? QT : KwT;
    int i = idx & 65535;
    int h = i >> 10;         // 0..63
    int n = i & 1023;        // 0..1023 (contiguous store)
    dst[h * 1024 + n] = f2bf(src[n * 64 + h]);
}

// prep_g: Gbt[j][i] = bf16(G[i][j]) (tiled transpose) + Grsum[i] = sum_j G[i][j]
__global__ void prep_g(const float* __restrict__ G, u16* __restrict__ Gbt,
                       float* __restrict__ Grsum) {
    __shared__ float tile[64][65];
    int i0 = blockIdx.y * 64, j0 = blockIdx.x * 64;
    int tx = threadIdx.x & 63, ty = threadIdx.x >> 6;   // ty 0..3
    for (int r = 0; r < 16; ++r) {
        int i = ty * 16 + r;
        tile[i][tx] = G[(size_t)(i0 + i) * 1024 + j0 + tx];
    }
    __syncthreads();
    for (int r = 0; r < 16; ++r) {
        int j = ty * 16 + r;
        Gbt[(size_t)(j0 + j) * 1024 + i0 + tx] = f2bf(tile[tx][j]);
    }
    if (ty == 0) {
        float sum = 0.f;
        for (int j = 0; j < 64; ++j) sum += tile[tx][j];
        atomicAdd(&Grsum[i0 + tx], sum);
    }
}

// ---------------------------------------------------------------------------
// gemm_qkt (split-K=4): reads fp32 s directly. Each block does K=256.
//   z <  16: q[b]  partial = S_b chunk @ Qw      A[m=node][k=i] : cast-stage
//   z >= 16: kt[b] partial = S_b^T chunk @ Kw    A[m=i][k=node] : transpose-stage
// Output: fp32 partials part[ks][z][m*64+h], reduced by reduce_qkt.
__global__ __launch_bounds__(256) void gemm_qkt(
        const float* __restrict__ s, const u16* __restrict__ QT,
        const u16* __restrict__ KwT, float* __restrict__ part) {
    int z = blockIdx.z; int b = z & 15; bool isq = (z < 16);
    int ks = blockIdx.y;                 // 0..3, K-range [ks*256, ks*256+256)
    int m0 = blockIdx.x * 128;
    __shared__ __align__(16) u16 As[128 * 40];
    __shared__ __align__(16) u16 Bs[64 * 40];
    const u16* Bt = isq ? QT : KwT;
    float* outp = part + (size_t)ks * 2097152 + (size_t)z * 65536;
    int t = threadIdx.x, lane = t & 63, w = t >> 6, quad = lane >> 4, l15 = lane & 15;
    f32x4 acc[2][4] = {};
    for (int kk = 0; kk < 8; ++kk) {
        int k0 = ks * 256 + kk * 32;
        {   // stage B tile 64x32 (bf16 global, padded write)
            int h = t >> 2, c = (t & 3) * 8;
            uint4 v = *(const uint4*)&Bt[(size_t)h * 1024 + k0 + c];
            *(uint4*)&Bs[h * 40 + c] = v;
        }
        if (isq) {          // A tile 128x32 from s rows, cast fp32->bf16
            int r = t >> 1, c = (t & 1) * 16;
            const float* src = s + (size_t)(m0 + r) * (BATCH * IN_DIM) + (size_t)b * IN_DIM + k0 + c;
            float4 f0 = ((const float4*)src)[0];
            float4 f1 = ((const float4*)src)[1];
            float4 f2 = ((const float4*)src)[2];
            float4 f3 = ((const float4*)src)[3];
            uint4 w0 = { pack2(f0.x,f0.y), pack2(f0.z,f0.w), pack2(f1.x,f1.y), pack2(f1.z,f1.w) };
            uint4 w1 = { pack2(f2.x,f2.y), pack2(f2.z,f2.w), pack2(f3.x,f3.y), pack2(f3.z,f3.w) };
            *(uint4*)&As[r * 40 + c]     = w0;
            *(uint4*)&As[r * 40 + c + 8] = w1;
        } else {            // A tile 128(i) x 32(n): transpose of s rows
            int nr = t >> 3, icb = (t & 7) * 4;
            const float* src = s + (size_t)(k0 + nr) * (BATCH * IN_DIM) + (size_t)b * IN_DIM + m0;
            for (int j3 = 0; j3 < 4; ++j3) {
                float4 f = *(const float4*)&src[icb + 32 * j3];
                As[(icb + 32*j3 + 0) * 40 + nr] = f2bf(f.x);
                As[(icb + 32*j3 + 1) * 40 + nr] = f2bf(f.y);
                As[(icb + 32*j3 + 2) * 40 + nr] = f2bf(f.z);
                As[(icb + 32*j3 + 3) * 40 + nr] = f2bf(f.w);
            }
        }
        __syncthreads();
        int kh = quad * 8;
        bf16x8 af[2], bfr[4];
        for (int rt = 0; rt < 2; ++rt) af[rt] = *(const bf16x8*)&As[(w*32 + rt*16 + l15) * 40 + kh];
        for (int ct = 0; ct < 4; ++ct) bfr[ct] = *(const bf16x8*)&Bs[(ct*16 + l15) * 40 + kh];
        for (int rt = 0; rt < 2; ++rt)
            for (int ct = 0; ct < 4; ++ct)
                acc[rt][ct] = __builtin_amdgcn_mfma_f32_16x16x32_bf16(af[rt], bfr[ct], acc[rt][ct], 0, 0, 0);
        __syncthreads();
    }
    for (int rt = 0; rt < 2; ++rt)
        for (int ct = 0; ct < 4; ++ct)
            for (int r = 0; r < 4; ++r) {
                int m = w * 32 + rt * 16 + quad * 4 + r;
                int n = ct * 16 + l15;
                outp[(size_t)(m0 + m) * 64 + n] = acc[rt][ct][r];
            }
}

// reduce_qkt: qkt_out[id(4 bf16)] = bf16(sum_ks part[ks][id(4 f32)])
__global__ void reduce_qkt(const float* __restrict__ part, u16* __restrict__ qkt_out) {
    int id = blockIdx.x * 256 + threadIdx.x;     // 0 .. 524287 (float4 index)
    const float4* p = (const float4*)part;
    float4 a = p[id];
    float4 b1 = p[id + 524288];
    float4 c = p[id + 1048576];
    float4 d = p[id + 1572864];
    a.x += b1.x + c.x + d.x; a.y += b1.y + c.y + d.y;
    a.z += b1.z + c.z + d.z; a.w += b1.w + c.w + d.w;
    uint2 pk = { pack2(a.x, a.y), pack2(a.z, a.w) };
    ((uint2*)qkt_out)[id] = pk;
}

// ---------------------------------------------------------------------------
// gemm_fused (BN=256): per (b, m-tile 128, n-tile 256):
//   K-loop over i (32/step): score chunk S^T(32i x 128m) = kt_chunk @ q^T (MFMA),
//   square(+1e-9), rowsum via Grsum identity, pack bf16 -> As (padded), then
//   agg k-step: acc += As(128x32) @ Gbt-chunk(256 rows). Epilogue: scale by
//   1/(rowsum+1e-3), write transposed (n,B,j) fp32 output. att never hits HBM.
// Score redundancy is 4x (vs 8x at BN=128); epilogue VALU per output halves.
__global__ __launch_bounds__(256, 2) void gemm_fused(
        const u16* __restrict__ qws, const u16* __restrict__ ktws,
        const u16* __restrict__ Gbt, const float* __restrict__ Grsum,
        float* __restrict__ out) {
    int b = blockIdx.z;
    int n0 = blockIdx.x * 256, m0 = blockIdx.y * 128;
    const u16* qb = qws  + (size_t)b * 65536;
    const u16* kb = ktws + (size_t)b * 65536;
    __shared__ __align__(16) u16 As[128 * 40];       // score->agg buffer, padded
    __shared__ __align__(16) u16 Bs[2][256 * 32];    // Gbt staging (gl_lds, dbuf)
    __shared__ __align__(16) u16 ktc[32 * 72];       // kt chunk, padded, single buf
    __shared__ __align__(16) float Grs[1024];
    __shared__ float rs[128];
    int t = threadIdx.x, lane = t & 63, w = t >> 6, quad = lane >> 4, l15 = lane & 15;
    int ti = w & 1;                              // score i-subtile (16 of 32)
    int wm = (w >> 1) * 64;                      // m-half (shared by score & agg)
    int wn = (w & 1) * 128;                      // agg n-half of 256

    ((float4*)Grs)[t] = ((const float4*)Grsum)[t];
    if (t < 128) rs[t] = 0.f;

    // K-invariant q B-frags: B[k=h][col=m], 8 contiguous h per lane
    bf16x8 qf[4][2];
    for (int j = 0; j < 4; ++j)
        for (int kick = 0; kick < 2; ++kick)
            qf[j][kick] = *(const bf16x8*)&qb[(size_t)(m0 + wm + j*16 + l15) * 64 + kick*32 + quad*8];

    // iter-0 staging: Gbt rows n0..n0+255, 32 cols
    int br = t >> 2, bc = (t & 3) * 8;
    for (int g4 = 0; g4 < 4; ++g4)
        gl_lds16(Gbt + (size_t)(n0 + br + g4*64) * 1024 + bc, &Bs[0][(br + g4*64) * 32 + bc]);
    int ir = t >> 3, ch = (t & 7) * 8;
    uint4 kreg = *(const uint4*)&kb[(size_t)ir * 64 + ch];

    f32x4 acc[4][8] = {};
    float partial[4] = {0.f, 0.f, 0.f, 0.f};

    for (int kk = 0; kk < 32; ++kk) {
        int buf = kk & 1;
        *(uint4*)&ktc[ir * 72 + ch] = kreg;        // single buf: prev reads done pre-barrier2
        __syncthreads();                           // barrier1: Bs[buf] + ktc ready
        // ---- score: S^T[i][m] for i-subtile ti, m in wave's 64-half
        f32x4 sacc[4] = {};
        for (int kick = 0; kick < 2; ++kick) {
            bf16x8 ktf = *(const bf16x8*)&ktc[(ti*16 + l15) * 72 + kick*32 + quad*8];
            for (int j = 0; j < 4; ++j)
                sacc[j] = __builtin_amdgcn_mfma_f32_16x16x32_bf16(ktf, qf[j][kick], sacc[j], 0, 0, 0);
        }
        if (kk < 31)
            kreg = *(const uint4*)&kb[(size_t)((kk + 1) * 32 + ir) * 64 + ch];
        // ---- epilogue: square, rowsum partial, pack to As
        float4 g = *(const float4*)&Grs[kk * 32 + ti * 16 + quad * 4];
        for (int j = 0; j < 4; ++j) {
            float v0 = sacc[j][0] * 0.125f + 1e-9f; v0 *= v0;
            float v1 = sacc[j][1] * 0.125f + 1e-9f; v1 *= v1;
            float v2 = sacc[j][2] * 0.125f + 1e-9f; v2 *= v2;
            float v3 = sacc[j][3] * 0.125f + 1e-9f; v3 *= v3;
            partial[j] += v0 * g.x + v1 * g.y + v2 * g.z + v3 * g.w;
            uint2 pk = { pack2(v0, v1), pack2(v2, v3) };
            *(uint2*)&As[(wm + j*16 + l15) * 40 + ti*16 + quad*4] = pk;
        }
        __syncthreads();                           // barrier2: As ready
        if (kk < 31) {                             // prefetch next Gbt chunk (in flight across agg)
            for (int g4 = 0; g4 < 4; ++g4)
                gl_lds16(Gbt + (size_t)(n0 + br + g4*64) * 1024 + (kk+1)*32 + bc,
                         &Bs[buf^1][(br + g4*64) * 32 + bc]);
        }
        // ---- agg k-step: wave's 64m x 128n
        int kh = quad * 8;
        bf16x8 af[4];
        for (int i = 0; i < 4; ++i) af[i] = *(const bf16x8*)&As[(wm + i*16 + l15) * 40 + kh];
        for (int jh = 0; jh < 2; ++jh) {
            bf16x8 bfr[4];
            for (int j = 0; j < 4; ++j)
                bfr[j] = *(const bf16x8*)&Bs[buf][(wn + jh*64 + j*16 + l15) * 32 + kh];
            for (int i = 0; i < 4; ++i)
                for (int j = 0; j < 4; ++j)
                    acc[i][jh*4 + j] = __builtin_amdgcn_mfma_f32_16x16x32_bf16(af[i], bfr[j], acc[i][jh*4 + j], 0, 0, 0);
        }
    }

    // rowsum: reduce quads (same m, different i-subsets), combine waves via LDS
    for (int j = 0; j < 4; ++j) {
        partial[j] += __shfl_xor(partial[j], 16, 64);
        partial[j] += __shfl_xor(partial[j], 32, 64);
    }
    if (quad == 0)
        for (int j = 0; j < 4; ++j) atomicAdd(&rs[wm + j*16 + l15], partial[j]);
    __syncthreads();
    if (t < 128) rs[t] = 1.0f / (rs[t] + 0.001f);
    __syncthreads();

    for (int i = 0; i < 4; ++i) {
        float4 rv = *(const float4*)&rs[wm + i * 16 + quad * 4];
        float rva[4] = { rv.x, rv.y, rv.z, rv.w };
        for (int r = 0; r < 4; ++r) {
            int m = m0 + wm + i * 16 + quad * 4 + r;
            float* orow = out + (size_t)m * (BATCH * IN_DIM) + (size_t)b * IN_DIM + n0 + wn;
            for (int j = 0; j < 8; ++j)
                orow[j * 16 + l15] = acc[i][j][r] * rva[r];
        }
    }
}

// ---------------------------------------------------------------------------
extern "C" void kernel_launch(void* const* d_in, const int* in_sizes, int n_in,
                              void* d_out, int out_size, void* d_ws, size_t ws_size,
                              hipStream_t stream) {
    const float* s  = (const float*)d_in[0];
    const float* G  = (const float*)d_in[1];
    const float* Q  = (const float*)d_in[2];
    const float* Kw = (const float*)d_in[3];
    float* out = (float*)d_out;
    char* ws = (char*)d_ws;

    float* part  = (float*)(ws);                                  // 32 MB (4 x 8 MB split-K partials)
    u16*   qws   = (u16*)(ws + (size_t)(32u << 20));              // 4 MB (q 2MB | kt 2MB)
    u16*   ktws  = qws + (size_t)16 * 65536;
    u16*   Gbt   = (u16*)(ws + (size_t)(36u << 20));              // 2 MB
    u16*   QT    = (u16*)(ws + (size_t)(38u << 20));              // 128 KB
    u16*   KwT   = (u16*)(ws + (size_t)(38u << 20) + (128u << 10)); // 128 KB
    float* Grsum = (float*)(ws + (size_t)(38u << 20) + (256u << 10)); // 4 KB

    hipMemsetAsync(Grsum, 0, 1024 * sizeof(float), stream);
    prep_w<<<512, 256, 0, stream>>>(Q, Kw, QT, KwT);
    prep_g<<<dim3(16, 16), 256, 0, stream>>>(G, Gbt, Grsum);
    gemm_qkt<<<dim3(8, 4, 32), 256, 0, stream>>>(s, QT, KwT, part);
    reduce_qkt<<<2048, 256, 0, stream>>>(part, qws);
    gemm_fused<<<dim3(4, 8, 16), 256, 0, stream>>>(qws, ktws, Gbt, Grsum, out);
}